// Round 13
// baseline (252.667 us; speedup 1.0000x reference)
//
#include <hip/hip_runtime.h>
#include <hip/hip_cooperative_groups.h>

namespace cg = cooperative_groups;

#define N_NODES 50000
#define NEDGE   400000
#define SB      512
#define NSB     ((N_NODES + SB - 1) / SB)   // 98 scan blocks
#define H8SCALE 128.0f                       // power-of-2: exactly undone in coeff

typedef __bf16 bf16x8 __attribute__((ext_vector_type(8)));
typedef float  f32x4  __attribute__((ext_vector_type(4)));
typedef float  f32x2  __attribute__((ext_vector_type(2)));
typedef unsigned short u16x8 __attribute__((ext_vector_type(8)));
typedef int    i32x2  __attribute__((ext_vector_type(2)));

#define GLDS16(gp, lp) \
  __builtin_amdgcn_global_load_lds((const __attribute__((address_space(1))) void*)(gp), \
                                   (__attribute__((address_space(3))) void*)(lp), 16, 0, 0)

static __device__ __forceinline__ unsigned short f2bf(float f) {
  unsigned u = __float_as_uint(f);
  unsigned r = (u + 0x7fffu + ((u >> 16) & 1u)) >> 16;   // RNE
  return (unsigned short)r;
}
static __device__ __forceinline__ float bf2f(unsigned short v) {
  return __uint_as_float((unsigned)v << 16);
}

// ---- fused front end: prep (blocks 0..511) | cast (512..2559) | count (2560..5684) ----
__global__ __launch_bounds__(256) void fused0_kernel(
    const float* __restrict__ basis, const float* __restrict__ att,
    const float* __restrict__ theta1, const float* __restrict__ theta2,
    const float* __restrict__ bias1, const float* __restrict__ bias2,
    unsigned short* __restrict__ Wt, float* __restrict__ biasvec,
    const float* __restrict__ node, unsigned short* __restrict__ A16,
    const int* __restrict__ adjp, const int* __restrict__ adjn,
    int* __restrict__ cntp, int* __restrict__ cntn) {
  const int b = blockIdx.x;
  if (b < 512) {
    // ---- prep: Wt[r*256+n][k] = (Wr[r] @ theta_r)[k][n], bf16; 4-way ILP ----
    const int r = b >> 8, k = b & 255;
    const int n = threadIdx.x;
    const float a0 = att[r * 2 + 0], a1 = att[r * 2 + 1];
    const float* th = (r == 0) ? theta1 : theta2;
    const float* b0 = basis + k * 256;
    const float* b1p = basis + 65536 + k * 256;
    float ac0 = 0.f, ac1 = 0.f, ac2 = 0.f, ac3 = 0.f;
    for (int j = 0; j < 256; j += 4) {
      const float w0 = a0 * b0[j + 0] + a1 * b1p[j + 0];
      const float w1 = a0 * b0[j + 1] + a1 * b1p[j + 1];
      const float w2 = a0 * b0[j + 2] + a1 * b1p[j + 2];
      const float w3 = a0 * b0[j + 3] + a1 * b1p[j + 3];
      ac0 += w0 * th[(j + 0) * 256 + n];
      ac1 += w1 * th[(j + 1) * 256 + n];
      ac2 += w2 * th[(j + 2) * 256 + n];
      ac3 += w3 * th[(j + 3) * 256 + n];
    }
    Wt[(size_t)(r * 256 + n) * 256 + k] = f2bf((ac0 + ac1) + (ac2 + ac3));
    if (k == 0) biasvec[r * 256 + n] = (r == 0) ? bias1[n] : bias2[n];
  } else if (b < 2560) {
    // ---- cast node_reps f32 -> bf16 ----
    const long total = (long)N_NODES * 256 / 4;
    long idx = (long)(b - 512) * 256 + threadIdx.x;
    const long stride = 2048L * 256;
    for (; idx < total; idx += stride) {
      const f32x4 v = __builtin_nontemporal_load(&((const f32x4*)node)[idx]);
      ushort4 o;
      o.x = f2bf(v.x); o.y = f2bf(v.y); o.z = f2bf(v.z); o.w = f2bf(v.w);
      ((ushort4*)A16)[idx] = o;
    }
  } else {
    // ---- count: per-row degree ----
    const int g = (b - 2560) * 256 + threadIdx.x;
    if (g < NEDGE) atomicAdd(&cntp[adjp[g]], 1);
    else if (g < 2 * NEDGE) atomicAdd(&cntn[adjn[g - NEDGE]], 1);
  }
}

// ---- GEMM: H8[M][512] = fp8(128 * (A @ W + bias)), bf16 MFMA; fused per-node dots (f32) ----
// XCD-swizzled block id (bijective, m204 form); sdbuf: [(sign*2+type)*4+slice][N]
__global__ __launch_bounds__(256) void gemm_kernel(
    const unsigned short* __restrict__ A,    // [M][256] bf16
    const unsigned short* __restrict__ Wt,   // [512][256] bf16 (N-major, i.e. B^T)
    const float* __restrict__ biasvec,       // [512]
    const float* __restrict__ mapping,       // [512]: w_src | w_dst
    unsigned char* __restrict__ H8,          // [M][512] fp8 e4m3, x128
    float* __restrict__ sdbuf) {
  __shared__ unsigned short smem[128 * 136];   // main loop: sA(8192)+sB(8192); epilogue: 128x136
  unsigned short* sA = smem;
  unsigned short* sB = smem + 8192;
  const int tid = threadIdx.x;
  const int wave = tid >> 6, lane = tid & 63;
  const int wm = wave >> 1, wn = wave & 1;
  const int bid = blockIdx.y * 4 + blockIdx.x;      // hw dispatch order (x fastest)
  const int xcd = bid & 7, loc = bid >> 3;
  const int nq = 1564 >> 3, nr = 1564 & 7;          // 195, 4
  const int swz = (xcd < nr ? xcd * (nq + 1) : nr * (nq + 1) + (xcd - nr) * nq) + loc;
  const int m0 = (swz >> 2) * 128;
  const int n0 = (swz & 3) * 128;

  f32x4 acc[4][4];
#pragma unroll
  for (int a = 0; a < 4; ++a)
#pragma unroll
    for (int b = 0; b < 4; ++b) acc[a][b] = (f32x4){0.f, 0.f, 0.f, 0.f};

  const int srow = lane >> 3;                      // 0..7
  const int skel = ((lane & 7) ^ srow) << 3;       // pre-swizzled source k element

  for (int ks = 0; ks < 4; ++ks) {
    const int kg = ks * 64 + skel;
#pragma unroll
    for (int c = 0; c < 4; ++c) {
      const int chunk = wave * 4 + c;              // 0..15
      const int row = chunk * 8 + srow;            // 0..127
      int rowg = m0 + row;
      rowg = rowg < N_NODES ? rowg : N_NODES - 1;  // clamp (writes are guarded)
      GLDS16(A + (size_t)rowg * 256 + kg, sA + chunk * 512);
      GLDS16(Wt + (size_t)(n0 + row) * 256 + kg, sB + chunk * 512);
    }
    __syncthreads();
#pragma unroll
    for (int kk = 0; kk < 2; ++kk) {
      const int kb = (kk * 32 + ((lane >> 4) << 3)) << 1;
      bf16x8 af[4], bfr[4];
#pragma unroll
      for (int m16 = 0; m16 < 4; ++m16) {
        const int row = wm * 64 + m16 * 16 + (lane & 15);
        af[m16] = *(const bf16x8*)((const char*)sA + row * 128 + (kb ^ ((row & 7) << 4)));
      }
#pragma unroll
      for (int n16 = 0; n16 < 4; ++n16) {
        const int col = wn * 64 + n16 * 16 + (lane & 15);
        bfr[n16] = *(const bf16x8*)((const char*)sB + col * 128 + (kb ^ ((col & 7) << 4)));
      }
#pragma unroll
      for (int m16 = 0; m16 < 4; ++m16)
#pragma unroll
        for (int n16 = 0; n16 < 4; ++n16)
          acc[m16][n16] = __builtin_amdgcn_mfma_f32_16x16x32_bf16(af[m16], bfr[n16], acc[m16][n16], 0, 0, 0);
    }
    __syncthreads();
  }

  // ---- epilogue: f32 dots to partial slices + bf16 tile via LDS -> coalesced fp8 H write ----
  const bool sgn = (n0 >= 256);
  const int nb = (sgn ? (n0 - 256) : n0) >> 7;   // 0..1
  const int slice = nb * 2 + wn;                 // 0..3
  float* __restrict__ sS = sdbuf + ((size_t)((sgn ? 2 : 0) + 0) * 4 + slice) * N_NODES;
  float* __restrict__ sD = sdbuf + ((size_t)((sgn ? 2 : 0) + 1) * 4 + slice) * N_NODES;
  float bv[4], wsv[4], wdv[4];
#pragma unroll
  for (int n16 = 0; n16 < 4; ++n16) {
    const int colg = n0 + wn * 64 + n16 * 16 + (lane & 15);
    bv[n16] = biasvec[colg];
    const int cm = colg & 255;
    wsv[n16] = mapping[cm];
    wdv[n16] = mapping[256 + cm];
  }
  // C/D layout: col=lane&15, row=(lane>>4)*4+j  [m89-verified]
#pragma unroll
  for (int m16 = 0; m16 < 4; ++m16) {
    const int rowb = wm * 64 + m16 * 16 + ((lane >> 4) << 2);   // block-local row
#pragma unroll
    for (int j = 0; j < 4; ++j) {
      const int rowl = rowb + j;
      float vs = 0.f, vd = 0.f;
#pragma unroll
      for (int n16 = 0; n16 < 4; ++n16) {
        const float v = acc[m16][n16][j] + bv[n16];
        const int coll = wn * 64 + n16 * 16 + (lane & 15);
        smem[rowl * 136 + coll] = f2bf(v);
        vs += v * wsv[n16];
        vd += v * wdv[n16];
      }
#pragma unroll
      for (int off = 1; off < 16; off <<= 1) { vs += __shfl_xor(vs, off); vd += __shfl_xor(vd, off); }
      const int rowg = m0 + rowl;
      if ((lane & 15) == 0 && rowg < N_NODES) { sS[rowg] = vs; sD[rowg] = vd; }
    }
  }
  __syncthreads();
#pragma unroll
  for (int it = 0; it < 8; ++it) {
    const int row = it * 16 + (tid >> 4);
    const int c8 = (tid & 15) * 8;
    const int rowg = m0 + row;
    if (rowg < N_NODES) {
      const u16x8 v = *(const u16x8*)(smem + row * 136 + c8);
      float f[8];
#pragma unroll
      for (int q = 0; q < 8; ++q) f[q] = bf2f((unsigned short)v[q]) * H8SCALE;
      int w0 = __builtin_amdgcn_cvt_pk_fp8_f32(f[0], f[1], 0, false);
      w0     = __builtin_amdgcn_cvt_pk_fp8_f32(f[2], f[3], w0, true);
      int w1 = __builtin_amdgcn_cvt_pk_fp8_f32(f[4], f[5], 0, false);
      w1     = __builtin_amdgcn_cvt_pk_fp8_f32(f[6], f[7], w1, true);
      i32x2 o; o.x = w0; o.y = w1;
      *(i32x2*)(&H8[(size_t)rowg * 512 + n0 + c8]) = o;
    }
  }
}

// ---- cooperative CSR kernel: scan1 | grid.sync | scan2+3 | grid.sync | scatter ----
__global__ __launch_bounds__(SB) void csr_kernel(
    const int* __restrict__ cntp, const int* __restrict__ cntn,
    int* __restrict__ bsp, int* __restrict__ bsn,
    const float* __restrict__ sdbuf,
    int* __restrict__ rsp, int* __restrict__ rsn,
    int* __restrict__ curp, int* __restrict__ curn,
    f32x4* __restrict__ nip, f32x4* __restrict__ nin,
    const int* __restrict__ adjp, const int* __restrict__ adjn,
    int* __restrict__ colp, int* __restrict__ coln) {
  cg::grid_group grid = cg::this_grid();
  __shared__ int sp_[SB], sn_[SB];
  __shared__ int pbs[128], nbs[128];
  const int t = threadIdx.x;
  const int i = blockIdx.x * SB + t;

  // ---- phase 1 (scan1): per-block partial sums ----
  {
    int vp = (i < N_NODES) ? cntp[i] : 0;
    int vn = (i < N_NODES) ? cntn[i] : 0;
#pragma unroll
    for (int off = 1; off < 64; off <<= 1) { vp += __shfl_xor(vp, off); vn += __shfl_xor(vn, off); }
    const int wv = t >> 6, lane = t & 63;
    if (lane == 0) { sp_[wv] = vp; sn_[wv] = vn; }
    __syncthreads();
    if (t == 0) {
      int ap = 0, an = 0;
#pragma unroll
      for (int w = 0; w < SB / 64; ++w) { ap += sp_[w]; an += sn_[w]; }
      bsp[blockIdx.x] = ap; bsn[blockIdx.x] = an;
    }
  }
  grid.sync();

  // ---- phase 2+3: redundant scan of 98 block sums + block scan -> rs/cur/nodeinfo ----
  if (t < 128) {
    pbs[t] = (t < NSB) ? bsp[t] : 0;
    nbs[t] = (t < NSB) ? bsn[t] : 0;
  }
  __syncthreads();
  for (int off = 1; off < 128; off <<= 1) {
    const int ap = (t >= off && t < 128) ? pbs[t - off] : 0;
    const int an = (t >= off && t < 128) ? nbs[t - off] : 0;
    __syncthreads();
    if (t < 128) { pbs[t] += ap; nbs[t] += an; }
    __syncthreads();
  }
  const int basep = (blockIdx.x == 0) ? 0 : pbs[blockIdx.x - 1];   // exclusive block offset
  const int basen = (blockIdx.x == 0) ? 0 : nbs[blockIdx.x - 1];
  if (blockIdx.x == 0 && t == 0) { rsp[N_NODES] = pbs[127]; rsn[N_NODES] = nbs[127]; }

  const int cp = (i < N_NODES) ? cntp[i] : 0;
  const int cn = (i < N_NODES) ? cntn[i] : 0;
  sp_[t] = cp; sn_[t] = cn;
  __syncthreads();
  for (int off = 1; off < SB; off <<= 1) {
    const int ap = (t >= off) ? sp_[t - off] : 0;
    const int an = (t >= off) ? sn_[t - off] : 0;
    __syncthreads();
    sp_[t] += ap; sn_[t] += an;
    __syncthreads();
  }
  if (i < N_NODES) {
    const int rp = basep + sp_[t] - cp;   // exclusive
    const int rn = basen + sn_[t] - cn;
    rsp[i] = rp; curp[i] = rp;
    rsn[i] = rn; curn[i] = rn;
    const float rdeg = 1.f / sqrtf((float)(cp + cn));
    float sp4 = 0.f, dp4 = 0.f, sn4 = 0.f, dn4 = 0.f;
#pragma unroll
    for (int sl = 0; sl < 4; ++sl) {
      sp4 += sdbuf[(size_t)(0 * 4 + sl) * N_NODES + i];
      dp4 += sdbuf[(size_t)(1 * 4 + sl) * N_NODES + i];
      sn4 += sdbuf[(size_t)(2 * 4 + sl) * N_NODES + i];
      dn4 += sdbuf[(size_t)(3 * 4 + sl) * N_NODES + i];
    }
    nip[i] = (f32x4){sp4, dp4, rdeg, 0.f};
    nin[i] = (f32x4){sn4, dn4, rdeg, 0.f};
  }
  grid.sync();

  // ---- phase 4 (scatter): grid-stride over 800K edges; col-only CSR ----
  const int stride = gridDim.x * SB;
  for (int g = blockIdx.x * SB + t; g < 2 * NEDGE; g += stride) {
    if (g < NEDGE) {
      const int src = adjp[g];
      colp[atomicAdd(&curp[src], 1)] = adjp[NEDGE + g];
    } else {
      const int e2 = g - NEDGE;
      const int src = adjn[e2];
      coln[atomicAdd(&curn[src], 1)] = adjn[NEDGE + e2];
    }
  }
}

// ---- aggregate: 2 rows/block, 2 waves/row (pos & neg parallel); inline coeff from nodeinfo ----
__global__ __launch_bounds__(256) void agg_kernel(
    const unsigned char* __restrict__ H8,
    const int* __restrict__ rsp, const int* __restrict__ colp,
    const int* __restrict__ rsn, const int* __restrict__ coln,
    const f32x4* __restrict__ nip, const f32x4* __restrict__ nin,
    const float* __restrict__ bias, float* __restrict__ out) {
  __shared__ f32x4 sneg[2][64];
  const int wave = threadIdx.x >> 6, lane = threadIdx.x & 63;
  const int r = wave >> 1;                 // 0..1  local row
  const int sign = wave & 1;               // 0 = pos, 1 = neg
  const int i = blockIdx.x * 2 + r;
  const int* __restrict__ rs  = sign ? rsn : rsp;
  const int* __restrict__ col = sign ? coln : colp;
  const f32x4* __restrict__ ni = sign ? nin : nip;
  const unsigned char* __restrict__ Hb = H8 + sign * 256 + (size_t)lane * 4;
  const f32x4 me = ni[i];
  const float srow = me.x;
  const float rdrow = me.z * (1.0f / H8SCALE);
  const int beg = rs[i], end = rs[i + 1];
  f32x4 a0 = {0,0,0,0}, a1 = {0,0,0,0}, a2 = {0,0,0,0}, a3 = {0,0,0,0};
  for (int chunk = beg; chunk < end; chunk += 64) {
    const int m = (end - chunk < 64) ? end - chunk : 64;
    int cv = 0;
    float fv = 0.f;                        // lanes >= m contribute 0
    if (lane < m) {
      cv = __builtin_nontemporal_load(&col[chunk + lane]);  // read-once stream
      const f32x4 nb = ni[cv];
      const float e = srow + nb.y;
      const float l = e > 0.f ? e : 0.2f * e;
      fv = (1.f / (1.f + expf(-l))) * rdrow * nb.z;
    }
    int k = 0;
    for (; k + 4 <= m; k += 4) {
      const int   c0 = __shfl(cv, k),     c1 = __shfl(cv, k + 1);
      const int   c2 = __shfl(cv, k + 2), c3 = __shfl(cv, k + 3);
      const float f0 = __shfl(fv, k),     f1 = __shfl(fv, k + 1);
      const float f2 = __shfl(fv, k + 2), f3 = __shfl(fv, k + 3);
      const unsigned w0 = *(const unsigned*)(Hb + (size_t)c0 * 512);
      const unsigned w1 = *(const unsigned*)(Hb + (size_t)c1 * 512);
      const unsigned w2 = *(const unsigned*)(Hb + (size_t)c2 * 512);
      const unsigned w3 = *(const unsigned*)(Hb + (size_t)c3 * 512);
      const f32x2 l0 = __builtin_amdgcn_cvt_pk_f32_fp8(w0, false), h0 = __builtin_amdgcn_cvt_pk_f32_fp8(w0, true);
      const f32x2 l1 = __builtin_amdgcn_cvt_pk_f32_fp8(w1, false), h1 = __builtin_amdgcn_cvt_pk_f32_fp8(w1, true);
      const f32x2 l2 = __builtin_amdgcn_cvt_pk_f32_fp8(w2, false), h2 = __builtin_amdgcn_cvt_pk_f32_fp8(w2, true);
      const f32x2 l3 = __builtin_amdgcn_cvt_pk_f32_fp8(w3, false), h3 = __builtin_amdgcn_cvt_pk_f32_fp8(w3, true);
      a0.x += f0 * l0.x; a0.y += f0 * l0.y; a0.z += f0 * h0.x; a0.w += f0 * h0.y;
      a1.x += f1 * l1.x; a1.y += f1 * l1.y; a1.z += f1 * h1.x; a1.w += f1 * h1.y;
      a2.x += f2 * l2.x; a2.y += f2 * l2.y; a2.z += f2 * h2.x; a2.w += f2 * h2.y;
      a3.x += f3 * l3.x; a3.y += f3 * l3.y; a3.z += f3 * h3.x; a3.w += f3 * h3.y;
    }
    for (; k < m; ++k) {
      const int   c0 = __shfl(cv, k);
      const float f0 = __shfl(fv, k);
      const unsigned w0 = *(const unsigned*)(Hb + (size_t)c0 * 512);
      const f32x2 l0 = __builtin_amdgcn_cvt_pk_f32_fp8(w0, false), h0 = __builtin_amdgcn_cvt_pk_f32_fp8(w0, true);
      a0.x += f0 * l0.x; a0.y += f0 * l0.y; a0.z += f0 * h0.x; a0.w += f0 * h0.y;
    }
  }
  f32x4 a = (a0 + a1) + (a2 + a3);
  if (sign) sneg[r][lane] = a;
  __syncthreads();
  if (sign) {
    __builtin_nontemporal_store(a, ((f32x4*)(out + (size_t)2 * N_NODES * 256)) + (size_t)i * 64 + lane);
  } else {
    const f32x4 an = sneg[r][lane];
    const f32x4 bv = ((const f32x4*)bias)[lane];
    const f32x4 o = a - an + bv;
    __builtin_nontemporal_store(o, ((f32x4*)out) + (size_t)i * 64 + lane);
    __builtin_nontemporal_store(a, ((f32x4*)(out + (size_t)N_NODES * 256)) + (size_t)i * 64 + lane);
  }
}

extern "C" void kernel_launch(void* const* d_in, const int* in_sizes, int n_in,
                              void* d_out, int out_size, void* d_ws, size_t ws_size,
                              hipStream_t stream) {
  const float* node    = (const float*)d_in[0];
  const int*   adjp    = (const int*)d_in[1];
  const int*   adjn    = (const int*)d_in[2];
  const float* basis   = (const float*)d_in[3];
  const float* att     = (const float*)d_in[4];
  const float* mapping = (const float*)d_in[5];
  const float* bias    = (const float*)d_in[6];
  const float* theta1  = (const float*)d_in[7];
  const float* b1      = (const float*)d_in[8];
  const float* theta2  = (const float*)d_in[9];
  const float* b2      = (const float*)d_in[10];
  float* out = (float*)d_out;

  size_t off = 0;
  char* wsb = (char*)d_ws;
  auto alloc = [&](size_t bytes) -> char* {
    char* p = wsb + off;
    off = (off + bytes + 255) & ~(size_t)255;
    return p;
  };
  unsigned short* A16 = (unsigned short*)alloc((size_t)N_NODES * 256 * 2);
  unsigned char*  H8  = (unsigned char*)alloc((size_t)N_NODES * 512);
  unsigned short* Wt  = (unsigned short*)alloc(512 * 256 * 2);
  float* biasvec = (float*)alloc(512 * 4);
  float* sdbuf = (float*)alloc((size_t)16 * N_NODES * 4);  // 16 partial-dot slices
  f32x4* nip = (f32x4*)alloc((size_t)N_NODES * 16);        // {s, d, rdeg, _} pos
  f32x4* nin = (f32x4*)alloc((size_t)N_NODES * 16);        // {s, d, rdeg, _} neg
  int* cnt2 = (int*)alloc((size_t)2 * N_NODES * 4);        // cntp | cntn (one memset)
  int* cntp = cnt2, *cntn = cnt2 + N_NODES;
  int* cur2 = (int*)alloc((size_t)2 * N_NODES * 4);        // initialized by csr phase 2
  int* curp = cur2, *curn = cur2 + N_NODES;
  int* rsp = (int*)alloc((N_NODES + 1) * 4);
  int* rsn = (int*)alloc((N_NODES + 1) * 4);
  int* bsp = (int*)alloc(NSB * 4);
  int* bsn = (int*)alloc(NSB * 4);
  int* colp = (int*)alloc((size_t)NEDGE * 4);              // CSR cols only
  int* coln = (int*)alloc((size_t)NEDGE * 4);

  (void)hipMemsetAsync(cnt2, 0, (size_t)2 * N_NODES * 4, stream);

  fused0_kernel<<<512 + 2048 + (2 * NEDGE) / 256, 256, 0, stream>>>(
      basis, att, theta1, theta2, b1, b2, Wt, biasvec, node, A16, adjp, adjn, cntp, cntn);
  gemm_kernel<<<dim3(4, 391), 256, 0, stream>>>(A16, Wt, biasvec, mapping, H8, sdbuf);
  {
    void* cargs[] = {(void*)&cntp, (void*)&cntn, (void*)&bsp, (void*)&bsn, (void*)&sdbuf,
                     (void*)&rsp, (void*)&rsn, (void*)&curp, (void*)&curn,
                     (void*)&nip, (void*)&nin, (void*)&adjp, (void*)&adjn,
                     (void*)&colp, (void*)&coln};
    (void)hipLaunchCooperativeKernel((void*)csr_kernel, dim3(NSB), dim3(SB), cargs, 0, stream);
  }
  agg_kernel<<<N_NODES / 2, 256, 0, stream>>>(H8, rsp, colp, rsn, coln, nip, nin, bias, out);
}

// Round 14
// 210.366 us; speedup vs baseline: 1.2011x; 1.2011x over previous
//
#include <hip/hip_runtime.h>

#define N_NODES 50000
#define NEDGE   400000
#define SB      512
#define NSB     ((N_NODES + SB - 1) / SB)   // 98 scan blocks
#define H8SCALE 128.0f                       // power-of-2: exactly undone in coeff

typedef __bf16 bf16x8 __attribute__((ext_vector_type(8)));
typedef float  f32x4  __attribute__((ext_vector_type(4)));
typedef float  f32x2  __attribute__((ext_vector_type(2)));
typedef unsigned short u16x8 __attribute__((ext_vector_type(8)));
typedef int    i32x2  __attribute__((ext_vector_type(2)));

#define GLDS16(gp, lp) \
  __builtin_amdgcn_global_load_lds((const __attribute__((address_space(1))) void*)(gp), \
                                   (__attribute__((address_space(3))) void*)(lp), 16, 0, 0)

static __device__ __forceinline__ unsigned short f2bf(float f) {
  unsigned u = __float_as_uint(f);
  unsigned r = (u + 0x7fffu + ((u >> 16) & 1u)) >> 16;   // RNE
  return (unsigned short)r;
}
static __device__ __forceinline__ float bf2f(unsigned short v) {
  return __uint_as_float((unsigned)v << 16);
}

// ---- fused front end: prep (blocks 0..511) | cast (512..2559) | count (2560..5684) ----
__global__ __launch_bounds__(256) void fused0_kernel(
    const float* __restrict__ basis, const float* __restrict__ att,
    const float* __restrict__ theta1, const float* __restrict__ theta2,
    const float* __restrict__ bias1, const float* __restrict__ bias2,
    unsigned short* __restrict__ Wt, float* __restrict__ biasvec,
    const float* __restrict__ node, unsigned short* __restrict__ A16,
    const int* __restrict__ adjp, const int* __restrict__ adjn,
    int* __restrict__ cntp, int* __restrict__ cntn) {
  const int b = blockIdx.x;
  if (b < 512) {
    // ---- prep: Wt[r*256+n][k] = (Wr[r] @ theta_r)[k][n], bf16; 4-way ILP ----
    const int r = b >> 8, k = b & 255;
    const int n = threadIdx.x;
    const float a0 = att[r * 2 + 0], a1 = att[r * 2 + 1];
    const float* th = (r == 0) ? theta1 : theta2;
    const float* b0 = basis + k * 256;
    const float* b1p = basis + 65536 + k * 256;
    float ac0 = 0.f, ac1 = 0.f, ac2 = 0.f, ac3 = 0.f;
    for (int j = 0; j < 256; j += 4) {
      const float w0 = a0 * b0[j + 0] + a1 * b1p[j + 0];
      const float w1 = a0 * b0[j + 1] + a1 * b1p[j + 1];
      const float w2 = a0 * b0[j + 2] + a1 * b1p[j + 2];
      const float w3 = a0 * b0[j + 3] + a1 * b1p[j + 3];
      ac0 += w0 * th[(j + 0) * 256 + n];
      ac1 += w1 * th[(j + 1) * 256 + n];
      ac2 += w2 * th[(j + 2) * 256 + n];
      ac3 += w3 * th[(j + 3) * 256 + n];
    }
    Wt[(size_t)(r * 256 + n) * 256 + k] = f2bf((ac0 + ac1) + (ac2 + ac3));
    if (k == 0) biasvec[r * 256 + n] = (r == 0) ? bias1[n] : bias2[n];
  } else if (b < 2560) {
    // ---- cast node_reps f32 -> bf16 ----
    const long total = (long)N_NODES * 256 / 4;
    long idx = (long)(b - 512) * 256 + threadIdx.x;
    const long stride = 2048L * 256;
    for (; idx < total; idx += stride) {
      const f32x4 v = __builtin_nontemporal_load(&((const f32x4*)node)[idx]);
      ushort4 o;
      o.x = f2bf(v.x); o.y = f2bf(v.y); o.z = f2bf(v.z); o.w = f2bf(v.w);
      ((ushort4*)A16)[idx] = o;
    }
  } else {
    // ---- count: per-row degree ----
    const int g = (b - 2560) * 256 + threadIdx.x;
    if (g < NEDGE) atomicAdd(&cntp[adjp[g]], 1);
    else if (g < 2 * NEDGE) atomicAdd(&cntn[adjn[g - NEDGE]], 1);
  }
}

// ---- GEMM: H8[M][512] = fp8(128 * (A @ W + bias)), bf16 MFMA; fused per-node dots (f32) ----
// sdbuf layout: [(sign*2 + type)*4 + slice][N]  type: 0 = s (w_src dot), 1 = d (w_dst dot)
__global__ __launch_bounds__(256) void gemm_kernel(
    const unsigned short* __restrict__ A,    // [M][256] bf16
    const unsigned short* __restrict__ Wt,   // [512][256] bf16 (N-major, i.e. B^T)
    const float* __restrict__ biasvec,       // [512]
    const float* __restrict__ mapping,       // [512]: w_src | w_dst
    unsigned char* __restrict__ H8,          // [M][512] fp8 e4m3, x128
    float* __restrict__ sdbuf) {
  __shared__ unsigned short smem[128 * 136];   // main loop: sA(8192)+sB(8192); epilogue: 128x136
  unsigned short* sA = smem;
  unsigned short* sB = smem + 8192;
  const int tid = threadIdx.x;
  const int wave = tid >> 6, lane = tid & 63;
  const int wm = wave >> 1, wn = wave & 1;
  const int m0 = blockIdx.y * 128;
  const int n0 = blockIdx.x * 128;

  f32x4 acc[4][4];
#pragma unroll
  for (int a = 0; a < 4; ++a)
#pragma unroll
    for (int b = 0; b < 4; ++b) acc[a][b] = (f32x4){0.f, 0.f, 0.f, 0.f};

  const int srow = lane >> 3;                      // 0..7
  const int skel = ((lane & 7) ^ srow) << 3;       // pre-swizzled source k element

  for (int ks = 0; ks < 4; ++ks) {
    const int kg = ks * 64 + skel;
#pragma unroll
    for (int c = 0; c < 4; ++c) {
      const int chunk = wave * 4 + c;              // 0..15
      const int row = chunk * 8 + srow;            // 0..127
      int rowg = m0 + row;
      rowg = rowg < N_NODES ? rowg : N_NODES - 1;  // clamp (writes are guarded)
      GLDS16(A + (size_t)rowg * 256 + kg, sA + chunk * 512);
      GLDS16(Wt + (size_t)(n0 + row) * 256 + kg, sB + chunk * 512);
    }
    __syncthreads();
#pragma unroll
    for (int kk = 0; kk < 2; ++kk) {
      const int kb = (kk * 32 + ((lane >> 4) << 3)) << 1;
      bf16x8 af[4], bfr[4];
#pragma unroll
      for (int m16 = 0; m16 < 4; ++m16) {
        const int row = wm * 64 + m16 * 16 + (lane & 15);
        af[m16] = *(const bf16x8*)((const char*)sA + row * 128 + (kb ^ ((row & 7) << 4)));
      }
#pragma unroll
      for (int n16 = 0; n16 < 4; ++n16) {
        const int col = wn * 64 + n16 * 16 + (lane & 15);
        bfr[n16] = *(const bf16x8*)((const char*)sB + col * 128 + (kb ^ ((col & 7) << 4)));
      }
#pragma unroll
      for (int m16 = 0; m16 < 4; ++m16)
#pragma unroll
        for (int n16 = 0; n16 < 4; ++n16)
          acc[m16][n16] = __builtin_amdgcn_mfma_f32_16x16x32_bf16(af[m16], bfr[n16], acc[m16][n16], 0, 0, 0);
    }
    __syncthreads();
  }

  // ---- epilogue: f32 dots to partial slices + bf16 tile via LDS -> coalesced fp8 H write ----
  const bool sgn = (n0 >= 256);
  const int nb = (sgn ? (n0 - 256) : n0) >> 7;   // 0..1
  const int slice = nb * 2 + wn;                 // 0..3
  float* __restrict__ sS = sdbuf + ((size_t)((sgn ? 2 : 0) + 0) * 4 + slice) * N_NODES;
  float* __restrict__ sD = sdbuf + ((size_t)((sgn ? 2 : 0) + 1) * 4 + slice) * N_NODES;
  float bv[4], wsv[4], wdv[4];
#pragma unroll
  for (int n16 = 0; n16 < 4; ++n16) {
    const int colg = n0 + wn * 64 + n16 * 16 + (lane & 15);
    bv[n16] = biasvec[colg];
    const int cm = colg & 255;
    wsv[n16] = mapping[cm];
    wdv[n16] = mapping[256 + cm];
  }
  // C/D layout: col=lane&15, row=(lane>>4)*4+j  [m89-verified]
#pragma unroll
  for (int m16 = 0; m16 < 4; ++m16) {
    const int rowb = wm * 64 + m16 * 16 + ((lane >> 4) << 2);   // block-local row
#pragma unroll
    for (int j = 0; j < 4; ++j) {
      const int rowl = rowb + j;
      float vs = 0.f, vd = 0.f;
#pragma unroll
      for (int n16 = 0; n16 < 4; ++n16) {
        const float v = acc[m16][n16][j] + bv[n16];
        const int coll = wn * 64 + n16 * 16 + (lane & 15);
        smem[rowl * 136 + coll] = f2bf(v);
        vs += v * wsv[n16];
        vd += v * wdv[n16];
      }
#pragma unroll
      for (int off = 1; off < 16; off <<= 1) { vs += __shfl_xor(vs, off); vd += __shfl_xor(vd, off); }
      const int rowg = m0 + rowl;
      if ((lane & 15) == 0 && rowg < N_NODES) { sS[rowg] = vs; sD[rowg] = vd; }
    }
  }
  __syncthreads();
#pragma unroll
  for (int it = 0; it < 8; ++it) {
    const int row = it * 16 + (tid >> 4);
    const int c8 = (tid & 15) * 8;
    const int rowg = m0 + row;
    if (rowg < N_NODES) {
      const u16x8 v = *(const u16x8*)(smem + row * 136 + c8);
      float f[8];
#pragma unroll
      for (int q = 0; q < 8; ++q) f[q] = bf2f((unsigned short)v[q]) * H8SCALE;
      int w0 = __builtin_amdgcn_cvt_pk_fp8_f32(f[0], f[1], 0, false);
      w0     = __builtin_amdgcn_cvt_pk_fp8_f32(f[2], f[3], w0, true);
      int w1 = __builtin_amdgcn_cvt_pk_fp8_f32(f[4], f[5], 0, false);
      w1     = __builtin_amdgcn_cvt_pk_fp8_f32(f[6], f[7], w1, true);
      i32x2 o; o.x = w0; o.y = w1;
      *(i32x2*)(&H8[(size_t)rowg * 512 + n0 + c8]) = o;
    }
  }
}

// ---------------- scan phase 1: per-block partial sums ----------------
__global__ __launch_bounds__(SB) void scan1_kernel(const int* __restrict__ cntp,
                                                   const int* __restrict__ cntn,
                                                   int* __restrict__ bsp, int* __restrict__ bsn) {
  __shared__ int lp[SB / 64], ln[SB / 64];
  const int i = blockIdx.x * SB + threadIdx.x;
  int vp = (i < N_NODES) ? cntp[i] : 0;
  int vn = (i < N_NODES) ? cntn[i] : 0;
#pragma unroll
  for (int off = 1; off < 64; off <<= 1) { vp += __shfl_xor(vp, off); vn += __shfl_xor(vn, off); }
  const int wave = threadIdx.x >> 6, lane = threadIdx.x & 63;
  if (lane == 0) { lp[wave] = vp; ln[wave] = vn; }
  __syncthreads();
  if (threadIdx.x == 0) {
    int ap = 0, an = 0;
#pragma unroll
    for (int w = 0; w < SB / 64; ++w) { ap += lp[w]; an += ln[w]; }
    bsp[blockIdx.x] = ap; bsn[blockIdx.x] = an;
  }
}

// -- scan phase 2+3 fused: every block redundantly scans the 98 block sums in LDS, then
//    block scan + offset -> row starts, cursors, packed nodeinfo {s,d,rdeg} --
__global__ __launch_bounds__(SB) void scan3_kernel(const int* __restrict__ cntp,
                                                   const int* __restrict__ cntn,
                                                   const int* __restrict__ bsp,
                                                   const int* __restrict__ bsn,
                                                   const float* __restrict__ sdbuf,
                                                   int* __restrict__ rsp, int* __restrict__ rsn,
                                                   int* __restrict__ curp, int* __restrict__ curn,
                                                   f32x4* __restrict__ nip, f32x4* __restrict__ nin) {
  __shared__ int sp_[SB], sn_[SB];
  __shared__ int pbs[128], nbs[128];
  const int t = threadIdx.x;
  // redundant scan2: exclusive-scan the 98 raw block sums (all blocks do this)
  if (t < 128) {
    pbs[t] = (t < NSB) ? bsp[t] : 0;
    nbs[t] = (t < NSB) ? bsn[t] : 0;
  }
  __syncthreads();
  for (int off = 1; off < 128; off <<= 1) {
    const int ap = (t >= off && t < 128) ? pbs[t - off] : 0;
    const int an = (t >= off && t < 128) ? nbs[t - off] : 0;
    __syncthreads();
    if (t < 128) { pbs[t] += ap; nbs[t] += an; }
    __syncthreads();
  }
  const int basep = (blockIdx.x == 0) ? 0 : pbs[blockIdx.x - 1];   // exclusive block offset
  const int basen = (blockIdx.x == 0) ? 0 : nbs[blockIdx.x - 1];
  if (blockIdx.x == 0 && t == 0) { rsp[N_NODES] = pbs[127]; rsn[N_NODES] = nbs[127]; }

  const int i = blockIdx.x * SB + t;
  const int cp = (i < N_NODES) ? cntp[i] : 0;
  const int cn = (i < N_NODES) ? cntn[i] : 0;
  sp_[t] = cp; sn_[t] = cn;
  __syncthreads();
  for (int off = 1; off < SB; off <<= 1) {
    const int ap = (t >= off) ? sp_[t - off] : 0;
    const int an = (t >= off) ? sn_[t - off] : 0;
    __syncthreads();
    sp_[t] += ap; sn_[t] += an;
    __syncthreads();
  }
  if (i < N_NODES) {
    const int rp = basep + sp_[t] - cp;   // exclusive
    const int rn = basen + sn_[t] - cn;
    rsp[i] = rp; curp[i] = rp;
    rsn[i] = rn; curn[i] = rn;
    const float rdeg = 1.f / sqrtf((float)(cp + cn));
    float sp4 = 0.f, dp4 = 0.f, sn4 = 0.f, dn4 = 0.f;
#pragma unroll
    for (int sl = 0; sl < 4; ++sl) {
      sp4 += sdbuf[(size_t)(0 * 4 + sl) * N_NODES + i];
      dp4 += sdbuf[(size_t)(1 * 4 + sl) * N_NODES + i];
      sn4 += sdbuf[(size_t)(2 * 4 + sl) * N_NODES + i];
      dn4 += sdbuf[(size_t)(3 * 4 + sl) * N_NODES + i];
    }
    nip[i] = (f32x4){sp4, dp4, rdeg, 0.f};
    nin[i] = (f32x4){sn4, dn4, rdeg, 0.f};
  }
}

// -- scatter into CSR: coeff (incl. 1/H8SCALE) from 2 packed gathers; 8B {dst,coeff} store --
__global__ void scatter_kernel(const int* __restrict__ adjp, const int* __restrict__ adjn,
                               const f32x4* __restrict__ nip, const f32x4* __restrict__ nin,
                               int* __restrict__ curp, int* __restrict__ curn,
                               i32x2* __restrict__ ecp, i32x2* __restrict__ ecn) {
  const int g = blockIdx.x * blockDim.x + threadIdx.x;
  if (g >= 2 * NEDGE) return;
  const bool neg = (g >= NEDGE);
  const int e2 = neg ? g - NEDGE : g;
  const int* __restrict__ adj = neg ? adjn : adjp;
  const f32x4* __restrict__ ni = neg ? nin : nip;
  int* __restrict__ cur = neg ? curn : curp;
  i32x2* __restrict__ ec = neg ? ecn : ecp;
  const int src = adj[e2], dst = adj[NEDGE + e2];
  const f32x4 a = ni[src], b = ni[dst];
  const float e = a.x + b.y;
  const float l = e > 0.f ? e : 0.2f * e;
  const float c = (1.f / (1.f + expf(-l))) * a.z * b.z * (1.0f / H8SCALE);
  const int p = atomicAdd(&cur[src], 1);
  i32x2 w; w.x = dst; w.y = __float_as_int(c);
  ec[p] = w;
}

// ---- aggregate (round-7 best): 2 rows/block, 2 waves/row (pos & neg parallel), fp8 gathers ----
__global__ __launch_bounds__(256) void agg_kernel(
    const unsigned char* __restrict__ H8,
    const int* __restrict__ rsp, const i32x2* __restrict__ ecp,
    const int* __restrict__ rsn, const i32x2* __restrict__ ecn,
    const float* __restrict__ bias, float* __restrict__ out) {
  __shared__ f32x4 sneg[2][64];
  const int wave = threadIdx.x >> 6, lane = threadIdx.x & 63;
  const int r = wave >> 1;                 // 0..1  local row
  const int sign = wave & 1;               // 0 = pos, 1 = neg
  const int i = blockIdx.x * 2 + r;
  const int* __restrict__ rs  = sign ? rsn : rsp;
  const i32x2* __restrict__ ec = sign ? ecn : ecp;
  const unsigned char* __restrict__ Hb = H8 + sign * 256 + (size_t)lane * 4;
  const int beg = rs[i], end = rs[i + 1];
  f32x4 a0 = {0,0,0,0}, a1 = {0,0,0,0}, a2 = {0,0,0,0}, a3 = {0,0,0,0};
  for (int chunk = beg; chunk < end; chunk += 64) {
    const int m = (end - chunk < 64) ? end - chunk : 64;
    i32x2 ev = {0, 0};
    if (lane < m) ev = __builtin_nontemporal_load(&ec[chunk + lane]);  // read-once stream
    const int   cv = ev.x;
    const float fv = __int_as_float(ev.y);
    int k = 0;
    for (; k + 4 <= m; k += 4) {
      const int   c0 = __shfl(cv, k),     c1 = __shfl(cv, k + 1);
      const int   c2 = __shfl(cv, k + 2), c3 = __shfl(cv, k + 3);
      const float f0 = __shfl(fv, k),     f1 = __shfl(fv, k + 1);
      const float f2 = __shfl(fv, k + 2), f3 = __shfl(fv, k + 3);
      const unsigned w0 = *(const unsigned*)(Hb + (size_t)c0 * 512);
      const unsigned w1 = *(const unsigned*)(Hb + (size_t)c1 * 512);
      const unsigned w2 = *(const unsigned*)(Hb + (size_t)c2 * 512);
      const unsigned w3 = *(const unsigned*)(Hb + (size_t)c3 * 512);
      const f32x2 l0 = __builtin_amdgcn_cvt_pk_f32_fp8(w0, false), h0 = __builtin_amdgcn_cvt_pk_f32_fp8(w0, true);
      const f32x2 l1 = __builtin_amdgcn_cvt_pk_f32_fp8(w1, false), h1 = __builtin_amdgcn_cvt_pk_f32_fp8(w1, true);
      const f32x2 l2 = __builtin_amdgcn_cvt_pk_f32_fp8(w2, false), h2 = __builtin_amdgcn_cvt_pk_f32_fp8(w2, true);
      const f32x2 l3 = __builtin_amdgcn_cvt_pk_f32_fp8(w3, false), h3 = __builtin_amdgcn_cvt_pk_f32_fp8(w3, true);
      a0.x += f0 * l0.x; a0.y += f0 * l0.y; a0.z += f0 * h0.x; a0.w += f0 * h0.y;
      a1.x += f1 * l1.x; a1.y += f1 * l1.y; a1.z += f1 * h1.x; a1.w += f1 * h1.y;
      a2.x += f2 * l2.x; a2.y += f2 * l2.y; a2.z += f2 * h2.x; a2.w += f2 * h2.y;
      a3.x += f3 * l3.x; a3.y += f3 * l3.y; a3.z += f3 * h3.x; a3.w += f3 * h3.y;
    }
    for (; k < m; ++k) {
      const int   c0 = __shfl(cv, k);
      const float f0 = __shfl(fv, k);
      const unsigned w0 = *(const unsigned*)(Hb + (size_t)c0 * 512);
      const f32x2 l0 = __builtin_amdgcn_cvt_pk_f32_fp8(w0, false), h0 = __builtin_amdgcn_cvt_pk_f32_fp8(w0, true);
      a0.x += f0 * l0.x; a0.y += f0 * l0.y; a0.z += f0 * h0.x; a0.w += f0 * h0.y;
    }
  }
  f32x4 a = (a0 + a1) + (a2 + a3);
  if (sign) sneg[r][lane] = a;
  __syncthreads();
  if (sign) {
    __builtin_nontemporal_store(a, ((f32x4*)(out + (size_t)2 * N_NODES * 256)) + (size_t)i * 64 + lane);
  } else {
    const f32x4 an = sneg[r][lane];
    const f32x4 bv = ((const f32x4*)bias)[lane];
    const f32x4 o = a - an + bv;
    __builtin_nontemporal_store(o, ((f32x4*)out) + (size_t)i * 64 + lane);
    __builtin_nontemporal_store(a, ((f32x4*)(out + (size_t)N_NODES * 256)) + (size_t)i * 64 + lane);
  }
}

extern "C" void kernel_launch(void* const* d_in, const int* in_sizes, int n_in,
                              void* d_out, int out_size, void* d_ws, size_t ws_size,
                              hipStream_t stream) {
  const float* node    = (const float*)d_in[0];
  const int*   adjp    = (const int*)d_in[1];
  const int*   adjn    = (const int*)d_in[2];
  const float* basis   = (const float*)d_in[3];
  const float* att     = (const float*)d_in[4];
  const float* mapping = (const float*)d_in[5];
  const float* bias    = (const float*)d_in[6];
  const float* theta1  = (const float*)d_in[7];
  const float* b1      = (const float*)d_in[8];
  const float* theta2  = (const float*)d_in[9];
  const float* b2      = (const float*)d_in[10];
  float* out = (float*)d_out;

  size_t off = 0;
  char* wsb = (char*)d_ws;
  auto alloc = [&](size_t bytes) -> char* {
    char* p = wsb + off;
    off = (off + bytes + 255) & ~(size_t)255;
    return p;
  };
  unsigned short* A16 = (unsigned short*)alloc((size_t)N_NODES * 256 * 2);
  unsigned char*  H8  = (unsigned char*)alloc((size_t)N_NODES * 512);
  unsigned short* Wt  = (unsigned short*)alloc(512 * 256 * 2);
  float* biasvec = (float*)alloc(512 * 4);
  float* sdbuf = (float*)alloc((size_t)16 * N_NODES * 4);  // 16 partial-dot slices
  f32x4* nip = (f32x4*)alloc((size_t)N_NODES * 16);        // {s, d, rdeg, _} pos
  f32x4* nin = (f32x4*)alloc((size_t)N_NODES * 16);        // {s, d, rdeg, _} neg
  int* cnt2 = (int*)alloc((size_t)2 * N_NODES * 4);        // cntp | cntn (one memset)
  int* cntp = cnt2, *cntn = cnt2 + N_NODES;
  int* cur2 = (int*)alloc((size_t)2 * N_NODES * 4);        // initialized by scan3
  int* curp = cur2, *curn = cur2 + N_NODES;
  int* rsp = (int*)alloc((N_NODES + 1) * 4);
  int* rsn = (int*)alloc((N_NODES + 1) * 4);
  int* bsp = (int*)alloc(NSB * 4);
  int* bsn = (int*)alloc(NSB * 4);
  i32x2* ecp = (i32x2*)alloc((size_t)NEDGE * 8);           // packed {dst, coeff}
  i32x2* ecn = (i32x2*)alloc((size_t)NEDGE * 8);

  (void)hipMemsetAsync(cnt2, 0, (size_t)2 * N_NODES * 4, stream);

  fused0_kernel<<<512 + 2048 + (2 * NEDGE) / 256, 256, 0, stream>>>(
      basis, att, theta1, theta2, b1, b2, Wt, biasvec, node, A16, adjp, adjn, cntp, cntn);
  gemm_kernel<<<dim3(4, 391), 256, 0, stream>>>(A16, Wt, biasvec, mapping, H8, sdbuf);
  scan1_kernel<<<NSB, SB, 0, stream>>>(cntp, cntn, bsp, bsn);
  scan3_kernel<<<NSB, SB, 0, stream>>>(cntp, cntn, bsp, bsn, sdbuf, rsp, rsn, curp, curn, nip, nin);
  scatter_kernel<<<(2 * NEDGE) / 256, 256, 0, stream>>>(adjp, adjn, nip, nin, curp, curn, ecp, ecn);
  agg_kernel<<<N_NODES / 2, 256, 0, stream>>>(H8, rsp, ecp, rsn, ecn, bias, out);
}